// Round 13
// baseline (490.455 us; speedup 1.0000x reference)
//
#include <hip/hip_runtime.h>
#include <hip/hip_bf16.h>

#define BB 4
#define LL 2048
#define DD 512
#define HH 8
#define HD 64
#define UU 8
#define BH (BB*HH)
#define SCALE 0.125f
#define ASCALE 0.18033688011112042f   // 0.125 * log2(e)

typedef __attribute__((ext_vector_type(8))) short short8;
typedef __attribute__((ext_vector_type(4))) float f32x4;
typedef unsigned short ushortT;

#define GLDS(gp, lp) __builtin_amdgcn_global_load_lds( \
    (const __attribute__((address_space(1))) void*)(gp), \
    (__attribute__((address_space(3))) void*)(lp), 16, 0, 0)

__device__ __forceinline__ unsigned short bf16_rne(float x) {
    unsigned int u = __float_as_uint(x);
    unsigned int r = u + 0x7FFFu + ((u >> 16) & 1u);
    return (unsigned short)(r >> 16);
}

// ---- K0: fused {kv partial sums} + {K split-bf16 images} + {Wfull fill} ----
__global__ __launch_bounds__(256) void prep_fill(const float* __restrict__ Kin,
                                                 const float* __restrict__ Vin,
                                                 float* __restrict__ vsum_part,
                                                 float* __restrict__ ksum_part,
                                                 ushortT* __restrict__ KhiG,
                                                 ushortT* __restrict__ KloG,
                                                 f32x4* __restrict__ Wz,
                                                 int* __restrict__ map,
                                                 int* __restrict__ cnt) {
    int t = threadIdx.x;
    if (blockIdx.x >= 1280) {                  // ---- fill path ----
        int fid = blockIdx.x - 1280;
        const f32x4 z = {0.f, 0.f, 0.f, 0.f};
        size_t base = (size_t)fid*256 + t;
        const size_t stride = (size_t)8192*256;
        #pragma unroll
        for (int i = 0; i < 16; i++)
            Wz[base + (size_t)i*stride] = z;
        if (fid == 0) {
            #pragma unroll
            for (int j = 0; j < 32; j++) map[t + j*256] = 0;
            if (t < 32) cnt[t] = 0;
        }
        return;
    }
    if (blockIdx.x < 256) {                    // ---- kv partial-sum path ----
        int blk = blockIdx.x;
        int bh = blk & 31, chunk = blk >> 5;
        int b = bh / HH, h = bh % HH;
        int d = t & 63; int g = t >> 6;
        const float* kb = Kin + (size_t)b*LL*DD + h*HD + d;
        const float* vb = Vin + (size_t)b*LL*DD + h*HD + d;
        float ak = 0.f, av = 0.f;
        for (int l = chunk*256 + g; l < chunk*256 + 256; l += 4) {
            ak += kb[(size_t)l*DD]; av += vb[(size_t)l*DD];
        }
        __shared__ float sk[4][64], sv[4][64];
        sk[g][d] = ak; sv[g][d] = av;
        __syncthreads();
        if (g == 0) {
            ksum_part[chunk*2048 + bh*64 + d] = sk[0][d]+sk[1][d]+sk[2][d]+sk[3][d];
            vsum_part[chunk*2048 + bh*64 + d] = sv[0][d]+sv[1][d]+sv[2][d]+sv[3][d];
        }
        return;
    }
    int blk = blockIdx.x - 256;                // ---- K image path ----
    int bh = blk >> 5, tile = blk & 31;
    int b = bh / HH, h = bh % HH;
    const float* kb = Kin + (size_t)b*LL*DD + h*HD;
    #pragma unroll
    for (int i = 0; i < 4; i++) {
        int f = t + i*256;
        int row = f >> 4, col4 = f & 15;
        float4 kv = *(const float4*)(kb + (size_t)(tile*64 + row)*DD + col4*4);
        float xs[4] = {kv.x, kv.y, kv.z, kv.w};
        unsigned short hb[4], lb[4];
        #pragma unroll
        for (int j = 0; j < 4; j++) {
            unsigned short hh = bf16_rne(xs[j]);
            float hf = __uint_as_float((unsigned int)hh << 16);
            hb[j] = hh; lb[j] = bf16_rne(xs[j] - hf);
        }
        int off = row*64 + (((col4>>1) ^ (row&7))<<3) + (col4&1)*4;
        uint2 uh; uh.x = hb[0] | ((unsigned)hb[1]<<16); uh.y = hb[2] | ((unsigned)hb[3]<<16);
        uint2 ul; ul.x = lb[0] | ((unsigned)lb[1]<<16); ul.y = lb[2] | ((unsigned)lb[3]<<16);
        *(uint2*)&KhiG[(size_t)blk*4096 + off] = uh;
        *(uint2*)&KloG[(size_t)blk*4096 + off] = ul;
    }
}

// ---- K2: M_measure (R11 structure) + fused last-block top-8 ---------------
__global__ __launch_bounds__(256) void m_mfma(const float* __restrict__ Q,
                                              const ushortT* __restrict__ KhiG,
                                              const ushortT* __restrict__ KloG,
                                              const float* __restrict__ ksum_part,
                                              float* __restrict__ M,
                                              int* __restrict__ cnt,
                                              int* __restrict__ idx,
                                              int* __restrict__ map) {
    int qt = blockIdx.x;
    int bh = blockIdx.y; int b = bh / HH, h = bh % HH;
    const int t = threadIdx.x;
    const int lane = t & 63, w = t >> 6;
    const int c = lane & 15, G = lane >> 4;

    __shared__ unsigned short kHi[2][4096];
    __shared__ unsigned short kLo[2][4096];
    __shared__ float ksLds[64];
    __shared__ float sm[128];
    __shared__ int elected;

    const float* qb = Q + (size_t)b*LL*DD + h*HD;
    const char* khg = (const char*)(KhiG + (size_t)bh*32*4096);
    const char* klg = (const char*)(KloG + (size_t)bh*32*4096);

    short8 a_hi[2][2], a_lo[2][2];
    #pragma unroll
    for (int g = 0; g < 2; g++) {
        int qrow = qt*128 + w*32 + g*16 + c;
        const float* qr = qb + (size_t)qrow*DD + G*8;
        #pragma unroll
        for (int dh = 0; dh < 2; dh++) {
            float4 x0 = *(const float4*)(qr + dh*32);
            float4 x1 = *(const float4*)(qr + dh*32 + 4);
            float x[8] = {x0.x,x0.y,x0.z,x0.w, x1.x,x1.y,x1.z,x1.w};
            short8 hi, lo;
            #pragma unroll
            for (int j = 0; j < 8; j++) {
                float xs = x[j] * ASCALE;
                unsigned short hb = bf16_rne(xs);
                float hf = __uint_as_float((unsigned int)hb << 16);
                hi[j] = (short)hb;
                lo[j] = (short)bf16_rne(xs - hf);
            }
            a_hi[g][dh] = hi; a_lo[g][dh] = lo;
        }
    }
    if (t < 64) {
        float s = 0.f;
        #pragma unroll
        for (int cc = 0; cc < 8; cc++) s += ksum_part[cc*2048 + bh*64 + t];
        ksLds[t] = s;
    }

    // prologue: async-stage tile 0 into buf 0 (linear, pre-swizzled images)
    {
        char* dH = (char*)&kHi[0][0];
        char* dL = (char*)&kLo[0][0];
        unsigned o0 = w*1024, o1 = w*1024 + 4096;
        GLDS(khg + o0 + lane*16, dH + o0);
        GLDS(khg + o1 + lane*16, dH + o1);
        GLDS(klg + o0 + lane*16, dL + o0);
        GLDS(klg + o1 + lane*16, dL + o1);
    }
    float se[2][4] = {};
    __syncthreads();

    for (int r = 0; r < 32; r++) {
        int p = r & 1;
        if (r < 31) {                          // async prefetch next tile
            const char* sH = khg + (size_t)(r+1)*8192;
            const char* sL = klg + (size_t)(r+1)*8192;
            char* dH = (char*)&kHi[p^1][0];
            char* dL = (char*)&kLo[p^1][0];
            unsigned o0 = w*1024, o1 = w*1024 + 4096;
            GLDS(sH + o0 + lane*16, dH + o0);
            GLDS(sH + o1 + lane*16, dH + o1);
            GLDS(sL + o0 + lane*16, dL + o0);
            GLDS(sL + o1 + lane*16, dL + o1);
        }
        #pragma unroll
        for (int kt = 0; kt < 4; kt++) {
            int rowIn = kt*16 + c;
            int sw = rowIn & 7;
            int base = rowIn*64;
            short8 bh0 = *(const short8*)&kHi[p][base + ((G       ^ sw)<<3)];
            short8 bh1 = *(const short8*)&kHi[p][base + (((G + 4) ^ sw)<<3)];
            short8 bl0 = *(const short8*)&kLo[p][base + ((G       ^ sw)<<3)];
            short8 bl1 = *(const short8*)&kLo[p][base + (((G + 4) ^ sw)<<3)];
            #pragma unroll
            for (int g = 0; g < 2; g++) {
                f32x4 acc = {0.f, 0.f, 0.f, 0.f};
                acc = __builtin_amdgcn_mfma_f32_16x16x32_bf16(a_hi[g][0], bh0, acc, 0, 0, 0);
                acc = __builtin_amdgcn_mfma_f32_16x16x32_bf16(a_hi[g][1], bh1, acc, 0, 0, 0);
                acc = __builtin_amdgcn_mfma_f32_16x16x32_bf16(a_lo[g][0], bh0, acc, 0, 0, 0);
                acc = __builtin_amdgcn_mfma_f32_16x16x32_bf16(a_lo[g][1], bh1, acc, 0, 0, 0);
                acc = __builtin_amdgcn_mfma_f32_16x16x32_bf16(a_hi[g][0], bl0, acc, 0, 0, 0);
                acc = __builtin_amdgcn_mfma_f32_16x16x32_bf16(a_hi[g][1], bl1, acc, 0, 0, 0);
                #pragma unroll
                for (int q4 = 0; q4 < 4; q4++) se[g][q4] += exp2f(acc[q4]);
            }
        }
        __syncthreads();
    }

    #pragma unroll
    for (int g = 0; g < 2; g++)
        #pragma unroll
        for (int q4 = 0; q4 < 4; q4++) {
            float v = se[g][q4];
            v += __shfl_xor(v, 1);
            v += __shfl_xor(v, 2);
            v += __shfl_xor(v, 4);
            v += __shfl_xor(v, 8);
            se[g][q4] = v;
        }
    if (c == 0) {
        #pragma unroll
        for (int g = 0; g < 2; g++)
            #pragma unroll
            for (int q4 = 0; q4 < 4; q4++)
                sm[w*32 + g*16 + G*4 + q4] = se[g][q4];
    }
    __syncthreads();
    if (t < 128) {
        int qrow = qt*128 + t;
        const float* qr = qb + (size_t)qrow*DD;
        float dot = 0.f;
        for (int d0 = 0; d0 < 64; d0 += 4) {
            float4 qv = *(const float4*)(qr + d0);
            dot += qv.x*ksLds[d0] + qv.y*ksLds[d0+1] + qv.z*ksLds[d0+2] + qv.w*ksLds[d0+3];
        }
        M[bh*LL + qrow] = __logf(sm[t]) - __logf((float)LL) - dot * (SCALE/(float)LL);
    }

    // ---- fused top-8: last block per bh ----
    __threadfence();
    if (t == 0) {
        int old = atomicAdd(&cnt[bh], 1);
        elected = (old == 15) ? 1 : 0;
    }
    __syncthreads();
    if (!elected) return;
    __threadfence();
    float* Ml   = (float*)&kHi[0][0];          // 8 KB reuse
    float* vals = (float*)&kLo[0][0];          // 1 KB
    int*   vidx = (int*)  &kLo[0][2048];       // 1 KB
    const volatile float* Mv = M + (size_t)bh*LL;
    for (int i = t; i < LL; i += 256) Ml[i] = Mv[i];
    __syncthreads();
    for (int r2 = 0; r2 < UU; r2++) {
        float bv = -1e30f; int bi = 0;
        for (int i = t; i < LL; i += 256) {
            float v = Ml[i];
            if (v > bv) { bv = v; bi = i; }
        }
        vals[t] = bv; vidx[t] = bi;
        __syncthreads();
        for (int s = 128; s > 0; s >>= 1) {
            if (t < s) {
                if (vals[t+s] > vals[t] ||
                    (vals[t+s] == vals[t] && vidx[t+s] < vidx[t])) {
                    vals[t] = vals[t+s]; vidx[t] = vidx[t+s];
                }
            }
            __syncthreads();
        }
        if (t == 0) {
            int wi = vidx[0];
            idx[bh*UU + r2] = wi;
            Ml[wi] = -1e30f;
            atomicOr(&map[(bh/HH)*LL + wi], 1 << (bh % HH));
        }
        __syncthreads();
    }
}

// ---------------- K4: active-row attention (reg-dbuf QK^T, float4 PV) ------
__global__ __launch_bounds__(256) void active_attn(const float* __restrict__ Q,
                                                   const float* __restrict__ Kin,
                                                   const float* __restrict__ Vin,
                                                   const int* __restrict__ idx,
                                                   const float* __restrict__ vsum_part,
                                                   const float* __restrict__ w_out,
                                                   const float* __restrict__ b_out,
                                                   float* __restrict__ attn_o,
                                                   float* __restrict__ defo,
                                                   float* __restrict__ Wfull) {
    __shared__ float qs[64];
    __shared__ float w[LL];
    __shared__ float red[256];
    __shared__ float Kt[256][65];
    __shared__ float red4[16][16][4];
    int t = threadIdx.x;
    if (blockIdx.x >= BH*UU) {             // ---- default-output path ----
        int b = blockIdx.x - BH*UU;
        for (int i = t; i < DD; i += 256) {
            float s = 0.f;
            #pragma unroll
            for (int cc = 0; cc < 8; cc++)
                s += vsum_part[cc*2048 + (b*HH + (i >> 6))*64 + (i & 63)];
            w[i] = s * (1.0f/LL);
        }
        __syncthreads();
        for (int dp = t; dp < DD; dp += 256) {
            const float* wr = w_out + (size_t)dp*DD;
            float acc = b_out[dp];
            for (int d0 = 0; d0 < DD; d0 += 4) {
                float4 wv = *(const float4*)(wr + d0);
                acc += w[d0]*wv.x + w[d0+1]*wv.y + w[d0+2]*wv.z + w[d0+3]*wv.w;
            }
            defo[b*DD + dp] = acc;
        }
        return;
    }
    int e = blockIdx.x;
    int bh = e / UU;
    int b = bh / HH, h = bh % HH;
    int l = idx[e];
    if (t < 64) qs[t] = Q[(size_t)b*LL*DD + (size_t)l*DD + h*HD + t];
    const float* kb = Kin + (size_t)b*LL*DD + h*HD;
    int srow = t >> 4, scol = t & 15;      // stage layout: 16 rows x 16 float4
    float4 nx[16];
    #pragma unroll
    for (int i = 0; i < 16; i++)
        nx[i] = *(const float4*)(kb + (size_t)(srow + i*16)*DD + scol*4);
    #pragma unroll
    for (int i = 0; i < 16; i++)
        *(float4*)&Kt[srow + i*16][scol*4] = nx[i];
    __syncthreads();

    float s[8];
    float mx = -1e30f;
    #pragma unroll
    for (int p = 0; p < 8; p++) {
        if (p < 7) {                       // prefetch next round into regs
            #pragma unroll
            for (int i = 0; i < 16; i++)
                nx[i] = *(const float4*)(kb + (size_t)((p+1)*256 + srow + i*16)*DD + scol*4);
        }
        float acc = 0.f;
        for (int d0 = 0; d0 < 64; d0 += 4) {
            acc += qs[d0]*Kt[t][d0] + qs[d0+1]*Kt[t][d0+1]
                 + qs[d0+2]*Kt[t][d0+2] + qs[d0+3]*Kt[t][d0+3];
        }
        s[p] = acc * SCALE;
        mx = fmaxf(mx, s[p]);
        __syncthreads();                   // done reading Kt
        if (p < 7) {
            #pragma unroll
            for (int i = 0; i < 16; i++)
                *(float4*)&Kt[srow + i*16][scol*4] = nx[i];
        }
        __syncthreads();                   // Kt ready for next round
    }
    red[t] = mx; __syncthreads();
    for (int st = 128; st > 0; st >>= 1) { if (t < st) red[t] = fmaxf(red[t], red[t+st]); __syncthreads(); }
    mx = red[0]; __syncthreads();
    float lsum = 0.f;
    #pragma unroll
    for (int p = 0; p < 8; p++) { s[p] = __expf(s[p] - mx); lsum += s[p]; }
    red[t] = lsum; __syncthreads();
    for (int st = 128; st > 0; st >>= 1) { if (t < st) red[t] += red[t+st]; __syncthreads(); }
    float inv = 1.0f / red[0]; __syncthreads();
    float* wrow = Wfull + ((size_t)bh*LL + l) * LL;
    #pragma unroll
    for (int p = 0; p < 8; p++) {
        int m = (p << 8) + t;
        float wn = s[p] * inv;
        w[m] = wn;
        wrow[m] = wn;
    }
    __syncthreads();
    // ---- PV: float4 loads, 1KB/wave-instr ----
    const float4* vb4 = (const float4*)(Vin + (size_t)b*LL*DD + h*HD);
    int grp = t >> 4, d4 = t & 15;
    f32x4 acc = {0.f, 0.f, 0.f, 0.f};
    for (int it = 0; it < 128; it++) {
        int m = grp + it*16;
        float4 v4 = vb4[(size_t)m*128 + d4];
        float wm = w[m];
        acc[0] += wm * v4.x; acc[1] += wm * v4.y;
        acc[2] += wm * v4.z; acc[3] += wm * v4.w;
    }
    *(f32x4*)&red4[grp][d4][0] = acc;
    __syncthreads();
    if (t < 64) {
        int dq = t >> 2, comp = t & 3;
        float sum = 0.f;
        #pragma unroll
        for (int g = 0; g < 16; g++) sum += red4[g][dq][comp];
        attn_o[e*64 + t] = sum;
    }
}

// ---------------- K6: assemble out = attn_output @ w_out^T + b_out ----------
__global__ __launch_bounds__(256) void out_kernel(const float* __restrict__ defo,
                                                  const float* __restrict__ vsum_part,
                                                  const float* __restrict__ attn_o,
                                                  const int* __restrict__ idx,
                                                  const int* __restrict__ map,
                                                  const float* __restrict__ w_out,
                                                  const float* __restrict__ b_out,
                                                  float* __restrict__ out) {
    int l = blockIdx.x, b = blockIdx.y;
    int t = threadIdx.x;
    float* orow = out + ((size_t)b*LL + l) * DD;
    int mp = map[b*LL + l];
    if (mp == 0) {
        const float* dr = defo + b*DD;
        orow[t] = dr[t]; orow[t + 256] = dr[t + 256];
        return;
    }
    __shared__ float x[DD];
    for (int i = t; i < DD; i += 256) {
        float s = 0.f;
        #pragma unroll
        for (int cc = 0; cc < 8; cc++)
            s += vsum_part[cc*2048 + (b*HH + (i >> 6))*64 + (i & 63)];
        x[i] = s * (1.0f/LL);
    }
    __syncthreads();
    if (t < 64) {
        for (int h = 0; h < HH; h++) if (mp & (1 << h)) {
            int bh = b*HH + h;
            int e = bh*UU;
            for (int j = 0; j < UU; j++) if (idx[bh*UU + j] == l) { e = bh*UU + j; break; }
            x[h*64 + t] = attn_o[e*64 + t];
        }
    }
    __syncthreads();
    for (int dp = t; dp < DD; dp += 256) {
        const float* wr = w_out + (size_t)dp*DD;
        float acc = b_out[dp];
        for (int d0 = 0; d0 < DD; d0 += 4) {
            float4 wv = *(const float4*)(wr + d0);
            acc += x[d0]*wv.x + x[d0+1]*wv.y + x[d0+2]*wv.z + x[d0+3]*wv.w;
        }
        orow[dp] = acc;
    }
}

extern "C" void kernel_launch(void* const* d_in, const int* in_sizes, int n_in,
                              void* d_out, int out_size, void* d_ws, size_t ws_size,
                              hipStream_t stream) {
    const float* Q     = (const float*)d_in[0];
    const float* Kin   = (const float*)d_in[1];
    const float* Vin   = (const float*)d_in[2];
    const float* w_out = (const float*)d_in[3];
    const float* b_out = (const float*)d_in[4];

    float* out   = (float*)d_out;
    float* Wfull = out + (size_t)BB*LL*DD;

    char* ws = (char*)d_ws;
    float*   vsum_part = (float*)(ws);                     // [8][32][64] 64KB
    float*   ksum_part = (float*)(ws + 65536);             // [8][32][64] 64KB
    float*   M         = (float*)(ws + 131072);            // [32][2048] 256KB
    int*     idx       = (int*)  (ws + 393216);            // [32][8]
    float*   attn_o    = (float*)(ws + 394240);            // [256][64] 64KB
    int*     map       = (int*)  (ws + 459776);            // [4][2048] 32KB
    float*   defo      = (float*)(ws + 493568);            // [4][512]  8KB
    int*     cnt       = (int*)  (ws + 501760);            // [32]
    ushortT* KhiG      = (ushortT*)(ws + (1u<<20));        // 8 MB tile images
    ushortT* KloG      = (ushortT*)(ws + (10u<<20));       // 8 MB

    prep_fill<<<9472, 256, 0, stream>>>(Kin, Vin, vsum_part, ksum_part,
                                        KhiG, KloG, (f32x4*)Wfull, map, cnt);
    m_mfma<<<dim3(16, BH), 256, 0, stream>>>(Q, KhiG, KloG, ksum_part, M, cnt, idx, map);
    active_attn<<<BH*UU + BB, 256, 0, stream>>>(Q, Kin, Vin, idx, vsum_part, w_out, b_out,
                                                attn_o, defo, Wfull);
    out_kernel<<<dim3(LL, BB), 256, 0, stream>>>(defo, vsum_part, attn_o, idx, map, w_out, b_out, out);
}

// Round 14
// 381.632 us; speedup vs baseline: 1.2852x; 1.2852x over previous
//
#include <hip/hip_runtime.h>
#include <hip/hip_bf16.h>

#define BB 4
#define LL 2048
#define DD 512
#define HH 8
#define HD 64
#define UU 8
#define BH (BB*HH)
#define SCALE 0.125f
#define ASCALE 0.18033688011112042f   // 0.125 * log2(e)

typedef __attribute__((ext_vector_type(8))) short short8;
typedef __attribute__((ext_vector_type(4))) float f32x4;
typedef unsigned short ushortT;

#define GLDS(gp, lp) __builtin_amdgcn_global_load_lds( \
    (const __attribute__((address_space(1))) void*)(gp), \
    (__attribute__((address_space(3))) void*)(lp), 16, 0, 0)

__device__ __forceinline__ unsigned short bf16_rne(float x) {
    unsigned int u = __float_as_uint(x);
    unsigned int r = u + 0x7FFFu + ((u >> 16) & 1u);
    return (unsigned short)(r >> 16);
}

// ---- K0: fused {kv partial sums (+map zero)} + {K split-bf16 images} ------
__global__ __launch_bounds__(256) void prep(const float* __restrict__ Kin,
                                            const float* __restrict__ Vin,
                                            float* __restrict__ vsum_part,
                                            float* __restrict__ ksum_part,
                                            ushortT* __restrict__ KhiG,
                                            ushortT* __restrict__ KloG,
                                            int* __restrict__ map) {
    int t = threadIdx.x;
    if (blockIdx.x < 256) {                    // ---- kv partial-sum path ----
        int blk = blockIdx.x;
        if (blk < 32) map[blk*256 + t] = 0;    // zero head map (8192 ints)
        int bh = blk & 31, chunk = blk >> 5;
        int b = bh / HH, h = bh % HH;
        int d = t & 63; int g = t >> 6;
        const float* kb = Kin + (size_t)b*LL*DD + h*HD + d;
        const float* vb = Vin + (size_t)b*LL*DD + h*HD + d;
        float ak = 0.f, av = 0.f;
        for (int l = chunk*256 + g; l < chunk*256 + 256; l += 4) {
            ak += kb[(size_t)l*DD]; av += vb[(size_t)l*DD];
        }
        __shared__ float sk[4][64], sv[4][64];
        sk[g][d] = ak; sv[g][d] = av;
        __syncthreads();
        if (g == 0) {
            ksum_part[chunk*2048 + bh*64 + d] = sk[0][d]+sk[1][d]+sk[2][d]+sk[3][d];
            vsum_part[chunk*2048 + bh*64 + d] = sv[0][d]+sv[1][d]+sv[2][d]+sv[3][d];
        }
        return;
    }
    int blk = blockIdx.x - 256;                // ---- K image path ----
    int bh = blk >> 5, tile = blk & 31;
    int b = bh / HH, h = bh % HH;
    const float* kb = Kin + (size_t)b*LL*DD + h*HD;
    #pragma unroll
    for (int i = 0; i < 4; i++) {
        int f = t + i*256;
        int row = f >> 4, col4 = f & 15;
        float4 kv = *(const float4*)(kb + (size_t)(tile*64 + row)*DD + col4*4);
        float xs[4] = {kv.x, kv.y, kv.z, kv.w};
        unsigned short hb[4], lb[4];
        #pragma unroll
        for (int j = 0; j < 4; j++) {
            unsigned short hh = bf16_rne(xs[j]);
            float hf = __uint_as_float((unsigned int)hh << 16);
            hb[j] = hh; lb[j] = bf16_rne(xs[j] - hf);
        }
        int off = row*64 + (((col4>>1) ^ (row&7))<<3) + (col4&1)*4;
        uint2 uh; uh.x = hb[0] | ((unsigned)hb[1]<<16); uh.y = hb[2] | ((unsigned)hb[3]<<16);
        uint2 ul; ul.x = lb[0] | ((unsigned)lb[1]<<16); ul.y = lb[2] | ((unsigned)lb[3]<<16);
        *(uint2*)&KhiG[(size_t)blk*4096 + off] = uh;
        *(uint2*)&KloG[(size_t)blk*4096 + off] = ul;
    }
}

// ---- K2: M_measure via split-bf16 MFMA; async global_load_lds staging -----
__global__ __launch_bounds__(256) void m_mfma(const float* __restrict__ Q,
                                              const ushortT* __restrict__ KhiG,
                                              const ushortT* __restrict__ KloG,
                                              const float* __restrict__ ksum_part,
                                              float* __restrict__ M) {
    int qt = blockIdx.x;
    int bh = blockIdx.y; int b = bh / HH, h = bh % HH;
    const int t = threadIdx.x;
    const int lane = t & 63, w = t >> 6;
    const int c = lane & 15, G = lane >> 4;

    __shared__ unsigned short kHi[2][4096];
    __shared__ unsigned short kLo[2][4096];
    __shared__ float ksLds[64];
    __shared__ float sm[128];

    const float* qb = Q + (size_t)b*LL*DD + h*HD;
    const char* khg = (const char*)(KhiG + (size_t)bh*32*4096);
    const char* klg = (const char*)(KloG + (size_t)bh*32*4096);

    short8 a_hi[2][2], a_lo[2][2];
    #pragma unroll
    for (int g = 0; g < 2; g++) {
        int qrow = qt*128 + w*32 + g*16 + c;
        const float* qr = qb + (size_t)qrow*DD + G*8;
        #pragma unroll
        for (int dh = 0; dh < 2; dh++) {
            float4 x0 = *(const float4*)(qr + dh*32);
            float4 x1 = *(const float4*)(qr + dh*32 + 4);
            float x[8] = {x0.x,x0.y,x0.z,x0.w, x1.x,x1.y,x1.z,x1.w};
            short8 hi, lo;
            #pragma unroll
            for (int j = 0; j < 8; j++) {
                float xs = x[j] * ASCALE;
                unsigned short hb = bf16_rne(xs);
                float hf = __uint_as_float((unsigned int)hb << 16);
                hi[j] = (short)hb;
                lo[j] = (short)bf16_rne(xs - hf);
            }
            a_hi[g][dh] = hi; a_lo[g][dh] = lo;
        }
    }
    if (t < 64) {
        float s = 0.f;
        #pragma unroll
        for (int cc = 0; cc < 8; cc++) s += ksum_part[cc*2048 + bh*64 + t];
        ksLds[t] = s;
    }

    // prologue: async-stage tile 0 into buf 0 (linear, pre-swizzled images)
    {
        char* dH = (char*)&kHi[0][0];
        char* dL = (char*)&kLo[0][0];
        unsigned o0 = w*1024, o1 = w*1024 + 4096;
        GLDS(khg + o0 + lane*16, dH + o0);
        GLDS(khg + o1 + lane*16, dH + o1);
        GLDS(klg + o0 + lane*16, dL + o0);
        GLDS(klg + o1 + lane*16, dL + o1);
    }
    float se[2][4] = {};
    __syncthreads();

    for (int r = 0; r < 32; r++) {
        int p = r & 1;
        if (r < 31) {                          // async prefetch next tile
            const char* sH = khg + (size_t)(r+1)*8192;
            const char* sL = klg + (size_t)(r+1)*8192;
            char* dH = (char*)&kHi[p^1][0];
            char* dL = (char*)&kLo[p^1][0];
            unsigned o0 = w*1024, o1 = w*1024 + 4096;
            GLDS(sH + o0 + lane*16, dH + o0);
            GLDS(sH + o1 + lane*16, dH + o1);
            GLDS(sL + o0 + lane*16, dL + o0);
            GLDS(sL + o1 + lane*16, dL + o1);
        }
        #pragma unroll
        for (int kt = 0; kt < 4; kt++) {
            int rowIn = kt*16 + c;
            int sw = rowIn & 7;
            int base = rowIn*64;
            short8 bh0 = *(const short8*)&kHi[p][base + ((G       ^ sw)<<3)];
            short8 bh1 = *(const short8*)&kHi[p][base + (((G + 4) ^ sw)<<3)];
            short8 bl0 = *(const short8*)&kLo[p][base + ((G       ^ sw)<<3)];
            short8 bl1 = *(const short8*)&kLo[p][base + (((G + 4) ^ sw)<<3)];
            #pragma unroll
            for (int g = 0; g < 2; g++) {
                f32x4 acc = {0.f, 0.f, 0.f, 0.f};
                acc = __builtin_amdgcn_mfma_f32_16x16x32_bf16(a_hi[g][0], bh0, acc, 0, 0, 0);
                acc = __builtin_amdgcn_mfma_f32_16x16x32_bf16(a_hi[g][1], bh1, acc, 0, 0, 0);
                acc = __builtin_amdgcn_mfma_f32_16x16x32_bf16(a_lo[g][0], bh0, acc, 0, 0, 0);
                acc = __builtin_amdgcn_mfma_f32_16x16x32_bf16(a_lo[g][1], bh1, acc, 0, 0, 0);
                acc = __builtin_amdgcn_mfma_f32_16x16x32_bf16(a_hi[g][0], bl0, acc, 0, 0, 0);
                acc = __builtin_amdgcn_mfma_f32_16x16x32_bf16(a_hi[g][1], bl1, acc, 0, 0, 0);
                #pragma unroll
                for (int q4 = 0; q4 < 4; q4++) se[g][q4] += exp2f(acc[q4]);
            }
        }
        __syncthreads();
    }

    #pragma unroll
    for (int g = 0; g < 2; g++)
        #pragma unroll
        for (int q4 = 0; q4 < 4; q4++) {
            float v = se[g][q4];
            v += __shfl_xor(v, 1);
            v += __shfl_xor(v, 2);
            v += __shfl_xor(v, 4);
            v += __shfl_xor(v, 8);
            se[g][q4] = v;
        }
    if (c == 0) {
        #pragma unroll
        for (int g = 0; g < 2; g++)
            #pragma unroll
            for (int q4 = 0; q4 < 4; q4++)
                sm[w*32 + g*16 + G*4 + q4] = se[g][q4];
    }
    __syncthreads();
    if (t < 128) {
        int qrow = qt*128 + t;
        const float* qr = qb + (size_t)qrow*DD;
        float dot = 0.f;
        for (int d0 = 0; d0 < 64; d0 += 4) {
            float4 qv = *(const float4*)(qr + d0);
            dot += qv.x*ksLds[d0] + qv.y*ksLds[d0+1] + qv.z*ksLds[d0+2] + qv.w*ksLds[d0+3];
        }
        M[bh*LL + qrow] = __logf(sm[t]) - __logf((float)LL) - dot * (SCALE/(float)LL);
    }
}

// ---------------- K3: top-8 per (b,h) + head-bit map scatter ----------------
__global__ __launch_bounds__(256) void top8(const float* __restrict__ M,
                                            int* __restrict__ idx,
                                            int* __restrict__ map) {
    int bh = blockIdx.x; int t = threadIdx.x;
    __shared__ float Ml[LL];
    __shared__ float vals[256];
    __shared__ int   vidx[256];
    for (int i = t; i < LL; i += 256) Ml[i] = M[bh*LL + i];
    __syncthreads();
    for (int r = 0; r < UU; r++) {
        float bv = -1e30f; int bi = 0;
        for (int i = t; i < LL; i += 256) {
            float v = Ml[i];
            if (v > bv) { bv = v; bi = i; }
        }
        vals[t] = bv; vidx[t] = bi;
        __syncthreads();
        for (int s = 128; s > 0; s >>= 1) {
            if (t < s) {
                if (vals[t+s] > vals[t] ||
                    (vals[t+s] == vals[t] && vidx[t+s] < vidx[t])) {
                    vals[t] = vals[t+s]; vidx[t] = vidx[t+s];
                }
            }
            __syncthreads();
        }
        if (t == 0) {
            int w = vidx[0];
            idx[bh*UU + r] = w;
            Ml[w] = -1e30f;
            atomicOr(&map[(bh/HH)*LL + w], 1 << (bh % HH));
        }
        __syncthreads();
    }
}

// ---------------- K4: active-row attention (reg-dbuf QK^T, float4 PV) ------
__global__ __launch_bounds__(256) void active_attn(const float* __restrict__ Q,
                                                   const float* __restrict__ Kin,
                                                   const float* __restrict__ Vin,
                                                   const int* __restrict__ idx,
                                                   const float* __restrict__ vsum_part,
                                                   const float* __restrict__ w_out,
                                                   const float* __restrict__ b_out,
                                                   float* __restrict__ attn_o,
                                                   float* __restrict__ defo,
                                                   float* __restrict__ Wfull) {
    __shared__ float qs[64];
    __shared__ float w[LL];
    __shared__ float red[256];
    __shared__ float Kt[256][65];
    __shared__ float red4[16][16][4];
    int t = threadIdx.x;
    if (blockIdx.x >= BH*UU) {             // ---- default-output path ----
        int b = blockIdx.x - BH*UU;
        for (int i = t; i < DD; i += 256) {
            float s = 0.f;
            #pragma unroll
            for (int cc = 0; cc < 8; cc++)
                s += vsum_part[cc*2048 + (b*HH + (i >> 6))*64 + (i & 63)];
            w[i] = s * (1.0f/LL);
        }
        __syncthreads();
        for (int dp = t; dp < DD; dp += 256) {
            const float* wr = w_out + (size_t)dp*DD;
            float acc = b_out[dp];
            for (int d0 = 0; d0 < DD; d0 += 4) {
                float4 wv = *(const float4*)(wr + d0);
                acc += w[d0]*wv.x + w[d0+1]*wv.y + w[d0+2]*wv.z + w[d0+3]*wv.w;
            }
            defo[b*DD + dp] = acc;
        }
        return;
    }
    int e = blockIdx.x;
    int bh = e / UU;
    int b = bh / HH, h = bh % HH;
    int l = idx[e];
    if (t < 64) qs[t] = Q[(size_t)b*LL*DD + (size_t)l*DD + h*HD + t];
    const float* kb = Kin + (size_t)b*LL*DD + h*HD;
    int srow = t >> 4, scol = t & 15;      // stage layout: 16 rows x 16 float4
    float4 nx[16];
    #pragma unroll
    for (int i = 0; i < 16; i++)
        nx[i] = *(const float4*)(kb + (size_t)(srow + i*16)*DD + scol*4);
    #pragma unroll
    for (int i = 0; i < 16; i++)
        *(float4*)&Kt[srow + i*16][scol*4] = nx[i];
    __syncthreads();

    float s[8];
    float mx = -1e30f;
    #pragma unroll
    for (int p = 0; p < 8; p++) {
        if (p < 7) {                       // prefetch next round into regs
            #pragma unroll
            for (int i = 0; i < 16; i++)
                nx[i] = *(const float4*)(kb + (size_t)((p+1)*256 + srow + i*16)*DD + scol*4);
        }
        float acc = 0.f;
        for (int d0 = 0; d0 < 64; d0 += 4) {
            acc += qs[d0]*Kt[t][d0] + qs[d0+1]*Kt[t][d0+1]
                 + qs[d0+2]*Kt[t][d0+2] + qs[d0+3]*Kt[t][d0+3];
        }
        s[p] = acc * SCALE;
        mx = fmaxf(mx, s[p]);
        __syncthreads();                   // done reading Kt
        if (p < 7) {
            #pragma unroll
            for (int i = 0; i < 16; i++)
                *(float4*)&Kt[srow + i*16][scol*4] = nx[i];
        }
        __syncthreads();                   // Kt ready for next round
    }
    red[t] = mx; __syncthreads();
    for (int st = 128; st > 0; st >>= 1) { if (t < st) red[t] = fmaxf(red[t], red[t+st]); __syncthreads(); }
    mx = red[0]; __syncthreads();
    float lsum = 0.f;
    #pragma unroll
    for (int p = 0; p < 8; p++) { s[p] = __expf(s[p] - mx); lsum += s[p]; }
    red[t] = lsum; __syncthreads();
    for (int st = 128; st > 0; st >>= 1) { if (t < st) red[t] += red[t+st]; __syncthreads(); }
    float inv = 1.0f / red[0]; __syncthreads();
    float* wrow = Wfull + ((size_t)bh*LL + l) * LL;
    #pragma unroll
    for (int p = 0; p < 8; p++) {
        int m = (p << 8) + t;
        float wn = s[p] * inv;
        w[m] = wn;
        wrow[m] = wn;
    }
    __syncthreads();
    // ---- PV: float4 loads, 1KB/wave-instr ----
    const float4* vb4 = (const float4*)(Vin + (size_t)b*LL*DD + h*HD);
    int grp = t >> 4, d4 = t & 15;
    f32x4 acc = {0.f, 0.f, 0.f, 0.f};
    for (int it = 0; it < 128; it++) {
        int m = grp + it*16;
        float4 v4 = vb4[(size_t)m*128 + d4];
        float wm = w[m];
        acc[0] += wm * v4.x; acc[1] += wm * v4.y;
        acc[2] += wm * v4.z; acc[3] += wm * v4.w;
    }
    *(f32x4*)&red4[grp][d4][0] = acc;
    __syncthreads();
    if (t < 64) {
        int dq = t >> 2, comp = t & 3;
        float sum = 0.f;
        #pragma unroll
        for (int g = 0; g < 16; g++) sum += red4[g][dq][comp];
        attn_o[e*64 + t] = sum;
    }
}

// ---- K6: out = attn_output @ w_out^T + b_out, fused Wfull zero-fill -------
__global__ __launch_bounds__(256) void out_kernel(const float* __restrict__ defo,
                                                  const float* __restrict__ vsum_part,
                                                  const float* __restrict__ attn_o,
                                                  const int* __restrict__ idx,
                                                  const int* __restrict__ map,
                                                  const float* __restrict__ w_out,
                                                  const float* __restrict__ b_out,
                                                  float* __restrict__ out,
                                                  float* __restrict__ Wfull) {
    int l = blockIdx.x, b = blockIdx.y;
    int t = threadIdx.x;

    // ---- fill portion: 8 Wfull rows per block, skip active rows ----
    {
        int fid = b*LL + l;                        // 0..8191
        f32x4* Wz = (f32x4*)Wfull;
        const f32x4 z = {0.f, 0.f, 0.f, 0.f};
        #pragma unroll
        for (int rr = 0; rr < 8; rr++) {
            int R = fid*8 + rr;                    // global Wfull row, 0..65535
            int bh2 = R >> 11, l2 = R & 2047;
            int b2 = bh2 >> 3, h2 = bh2 & 7;
            if (!((map[b2*LL + l2] >> h2) & 1)) {
                f32x4* rowp = Wz + (size_t)R*512;  // 2048 f32 = 512 f32x4
                rowp[t] = z;
                rowp[t + 256] = z;
            }
        }
    }

    // ---- output-row portion ----
    float* orow = out + ((size_t)b*LL + l) * DD;
    int mp = map[b*LL + l];
    if (mp == 0) {
        const float* dr = defo + b*DD;
        orow[t] = dr[t]; orow[t + 256] = dr[t + 256];
        return;
    }
    __shared__ float x[DD];
    for (int i = t; i < DD; i += 256) {
        float s = 0.f;
        #pragma unroll
        for (int cc = 0; cc < 8; cc++)
            s += vsum_part[cc*2048 + (b*HH + (i >> 6))*64 + (i & 63)];
        x[i] = s * (1.0f/LL);
    }
    __syncthreads();
    if (t < 64) {
        for (int h = 0; h < HH; h++) if (mp & (1 << h)) {
            int bh = b*HH + h;
            int e = bh*UU;
            for (int j = 0; j < UU; j++) if (idx[bh*UU + j] == l) { e = bh*UU + j; break; }
            x[h*64 + t] = attn_o[e*64 + t];
        }
    }
    __syncthreads();
    for (int dp = t; dp < DD; dp += 256) {
        const float* wr = w_out + (size_t)dp*DD;
        float acc = b_out[dp];
        for (int d0 = 0; d0 < DD; d0 += 4) {
            float4 wv = *(const float4*)(wr + d0);
            acc += x[d0]*wv.x + x[d0+1]*wv.y + x[d0+2]*wv.z + x[d0+3]*wv.w;
        }
        orow[dp] = acc;
    }
}

extern "C" void kernel_launch(void* const* d_in, const int* in_sizes, int n_in,
                              void* d_out, int out_size, void* d_ws, size_t ws_size,
                              hipStream_t stream) {
    const float* Q     = (const float*)d_in[0];
    const float* Kin   = (const float*)d_in[1];
    const float* Vin   = (const float*)d_in[2];
    const float* w_out = (const float*)d_in[3];
    const float* b_out = (const float*)d_in[4];

    float* out   = (float*)d_out;
    float* Wfull = out + (size_t)BB*LL*DD;

    char* ws = (char*)d_ws;
    float*   vsum_part = (float*)(ws);                     // [8][32][64] 64KB
    float*   ksum_part = (float*)(ws + 65536);             // [8][32][64] 64KB
    float*   M         = (float*)(ws + 131072);            // [32][2048] 256KB
    int*     idx       = (int*)  (ws + 393216);            // [32][8]
    float*   attn_o    = (float*)(ws + 394240);            // [256][64] 64KB
    int*     map       = (int*)  (ws + 459776);            // [4][2048] 32KB
    float*   defo      = (float*)(ws + 493568);            // [4][512]  8KB
    ushortT* KhiG      = (ushortT*)(ws + (1u<<20));        // 8 MB tile images
    ushortT* KloG      = (ushortT*)(ws + (10u<<20));       // 8 MB

    prep<<<1280, 256, 0, stream>>>(Kin, Vin, vsum_part, ksum_part, KhiG, KloG, map);
    m_mfma<<<dim3(16, BH), 256, 0, stream>>>(Q, KhiG, KloG, ksum_part, M);
    top8<<<BH, 256, 0, stream>>>(M, idx, map);
    active_attn<<<BH*UU + BB, 256, 0, stream>>>(Q, Kin, Vin, idx, vsum_part, w_out, b_out,
                                                attn_o, defo, Wfull);
    out_kernel<<<dim3(LL, BB), 256, 0, stream>>>(defo, vsum_part, attn_o, idx, map,
                                                 w_out, b_out, out, Wfull);
}

// Round 15
// 370.159 us; speedup vs baseline: 1.3250x; 1.0310x over previous
//
#include <hip/hip_runtime.h>
#include <hip/hip_bf16.h>

#define BB 4
#define LL 2048
#define DD 512
#define HH 8
#define HD 64
#define UU 8
#define BH (BB*HH)
#define SCALE 0.125f
#define ASCALE 0.18033688011112042f   // 0.125 * log2(e)

typedef __attribute__((ext_vector_type(8))) short short8;
typedef __attribute__((ext_vector_type(4))) float f32x4;
typedef unsigned short ushortT;

#define GLDS(gp, lp) __builtin_amdgcn_global_load_lds( \
    (const __attribute__((address_space(1))) void*)(gp), \
    (__attribute__((address_space(3))) void*)(lp), 16, 0, 0)

__device__ __forceinline__ unsigned short bf16_rne(float x) {
    unsigned int u = __float_as_uint(x);
    unsigned int r = u + 0x7FFFu + ((u >> 16) & 1u);
    return (unsigned short)(r >> 16);
}

// ---- K0: fused {kv partial sums (+map zero)} + {K hi-bf16 images} ---------
__global__ __launch_bounds__(256) void prep(const float* __restrict__ Kin,
                                            const float* __restrict__ Vin,
                                            float* __restrict__ vsum_part,
                                            float* __restrict__ ksum_part,
                                            ushortT* __restrict__ KhiG,
                                            int* __restrict__ map) {
    int t = threadIdx.x;
    if (blockIdx.x < 256) {                    // ---- kv partial-sum path ----
        int blk = blockIdx.x;
        if (blk < 32) map[blk*256 + t] = 0;    // zero head map (8192 ints)
        int bh = blk & 31, chunk = blk >> 5;
        int b = bh / HH, h = bh % HH;
        int d = t & 63; int g = t >> 6;
        const float* kb = Kin + (size_t)b*LL*DD + h*HD + d;
        const float* vb = Vin + (size_t)b*LL*DD + h*HD + d;
        float ak = 0.f, av = 0.f;
        for (int l = chunk*256 + g; l < chunk*256 + 256; l += 4) {
            ak += kb[(size_t)l*DD]; av += vb[(size_t)l*DD];
        }
        __shared__ float sk[4][64], sv[4][64];
        sk[g][d] = ak; sv[g][d] = av;
        __syncthreads();
        if (g == 0) {
            ksum_part[chunk*2048 + bh*64 + d] = sk[0][d]+sk[1][d]+sk[2][d]+sk[3][d];
            vsum_part[chunk*2048 + bh*64 + d] = sv[0][d]+sv[1][d]+sv[2][d]+sv[3][d];
        }
        return;
    }
    int blk = blockIdx.x - 256;                // ---- K hi-image path ----
    int bh = blk >> 5, tile = blk & 31;
    int b = bh / HH, h = bh % HH;
    const float* kb = Kin + (size_t)b*LL*DD + h*HD;
    #pragma unroll
    for (int i = 0; i < 4; i++) {
        int f = t + i*256;
        int row = f >> 4, col4 = f & 15;
        float4 kv = *(const float4*)(kb + (size_t)(tile*64 + row)*DD + col4*4);
        float xs[4] = {kv.x, kv.y, kv.z, kv.w};
        unsigned short hb[4];
        #pragma unroll
        for (int j = 0; j < 4; j++) hb[j] = bf16_rne(xs[j]);
        int off = row*64 + (((col4>>1) ^ (row&7))<<3) + (col4&1)*4;
        uint2 uh; uh.x = hb[0] | ((unsigned)hb[1]<<16); uh.y = hb[2] | ((unsigned)hb[3]<<16);
        *(uint2*)&KhiG[(size_t)blk*4096 + off] = uh;
    }
}

// ---- K2: M_measure via 2-term split-bf16 MFMA (k_hi only in LDS) ----------
__global__ __launch_bounds__(256) void m_mfma(const float* __restrict__ Q,
                                              const ushortT* __restrict__ KhiG,
                                              const float* __restrict__ ksum_part,
                                              float* __restrict__ M) {
    int qt = blockIdx.x;
    int bh = blockIdx.y; int b = bh / HH, h = bh % HH;
    const int t = threadIdx.x;
    const int lane = t & 63, w = t >> 6;
    const int c = lane & 15, G = lane >> 4;

    __shared__ unsigned short kHi[2][4096];
    __shared__ float ksLds[64];
    __shared__ float sm[128];

    const float* qb = Q + (size_t)b*LL*DD + h*HD;
    const char* khg = (const char*)(KhiG + (size_t)bh*32*4096);

    short8 a_hi[2][2], a_lo[2][2];
    #pragma unroll
    for (int g = 0; g < 2; g++) {
        int qrow = qt*128 + w*32 + g*16 + c;
        const float* qr = qb + (size_t)qrow*DD + G*8;
        #pragma unroll
        for (int dh = 0; dh < 2; dh++) {
            float4 x0 = *(const float4*)(qr + dh*32);
            float4 x1 = *(const float4*)(qr + dh*32 + 4);
            float x[8] = {x0.x,x0.y,x0.z,x0.w, x1.x,x1.y,x1.z,x1.w};
            short8 hi, lo;
            #pragma unroll
            for (int j = 0; j < 8; j++) {
                float xs = x[j] * ASCALE;
                unsigned short hb = bf16_rne(xs);
                float hf = __uint_as_float((unsigned int)hb << 16);
                hi[j] = (short)hb;
                lo[j] = (short)bf16_rne(xs - hf);
            }
            a_hi[g][dh] = hi; a_lo[g][dh] = lo;
        }
    }
    if (t < 64) {
        float s = 0.f;
        #pragma unroll
        for (int cc = 0; cc < 8; cc++) s += ksum_part[cc*2048 + bh*64 + t];
        ksLds[t] = s;
    }

    // prologue: async-stage tile 0 into buf 0 (linear, pre-swizzled image)
    {
        char* dH = (char*)&kHi[0][0];
        unsigned o0 = w*1024, o1 = w*1024 + 4096;
        GLDS(khg + o0 + lane*16, dH + o0);
        GLDS(khg + o1 + lane*16, dH + o1);
    }
    float se[2][4] = {};
    __syncthreads();

    for (int r = 0; r < 32; r++) {
        int p = r & 1;
        if (r < 31) {                          // async prefetch next tile
            const char* sH = khg + (size_t)(r+1)*8192;
            char* dH = (char*)&kHi[p^1][0];
            unsigned o0 = w*1024, o1 = w*1024 + 4096;
            GLDS(sH + o0 + lane*16, dH + o0);
            GLDS(sH + o1 + lane*16, dH + o1);
        }
        #pragma unroll
        for (int kt = 0; kt < 4; kt++) {
            int rowIn = kt*16 + c;
            int sw = rowIn & 7;
            int base = rowIn*64;
            short8 bh0 = *(const short8*)&kHi[p][base + ((G       ^ sw)<<3)];
            short8 bh1 = *(const short8*)&kHi[p][base + (((G + 4) ^ sw)<<3)];
            #pragma unroll
            for (int g = 0; g < 2; g++) {
                f32x4 acc = {0.f, 0.f, 0.f, 0.f};
                acc = __builtin_amdgcn_mfma_f32_16x16x32_bf16(a_hi[g][0], bh0, acc, 0, 0, 0);
                acc = __builtin_amdgcn_mfma_f32_16x16x32_bf16(a_hi[g][1], bh1, acc, 0, 0, 0);
                acc = __builtin_amdgcn_mfma_f32_16x16x32_bf16(a_lo[g][0], bh0, acc, 0, 0, 0);
                acc = __builtin_amdgcn_mfma_f32_16x16x32_bf16(a_lo[g][1], bh1, acc, 0, 0, 0);
                #pragma unroll
                for (int q4 = 0; q4 < 4; q4++) se[g][q4] += exp2f(acc[q4]);
            }
        }
        __syncthreads();
    }

    #pragma unroll
    for (int g = 0; g < 2; g++)
        #pragma unroll
        for (int q4 = 0; q4 < 4; q4++) {
            float v = se[g][q4];
            v += __shfl_xor(v, 1);
            v += __shfl_xor(v, 2);
            v += __shfl_xor(v, 4);
            v += __shfl_xor(v, 8);
            se[g][q4] = v;
        }
    if (c == 0) {
        #pragma unroll
        for (int g = 0; g < 2; g++)
            #pragma unroll
            for (int q4 = 0; q4 < 4; q4++)
                sm[w*32 + g*16 + G*4 + q4] = se[g][q4];
    }
    __syncthreads();
    if (t < 128) {
        int qrow = qt*128 + t;
        const float* qr = qb + (size_t)qrow*DD;
        float dot = 0.f;
        for (int d0 = 0; d0 < 64; d0 += 4) {
            float4 qv = *(const float4*)(qr + d0);
            dot += qv.x*ksLds[d0] + qv.y*ksLds[d0+1] + qv.z*ksLds[d0+2] + qv.w*ksLds[d0+3];
        }
        M[bh*LL + qrow] = __logf(sm[t]) - __logf((float)LL) - dot * (SCALE/(float)LL);
    }
}

// ---------------- K3: top-8 per (b,h) + head-bit map scatter ----------------
__global__ __launch_bounds__(256) void top8(const float* __restrict__ M,
                                            int* __restrict__ idx,
                                            int* __restrict__ map) {
    int bh = blockIdx.x; int t = threadIdx.x;
    __shared__ float Ml[LL];
    __shared__ float vals[256];
    __shared__ int   vidx[256];
    for (int i = t; i < LL; i += 256) Ml[i] = M[bh*LL + i];
    __syncthreads();
    for (int r = 0; r < UU; r++) {
        float bv = -1e30f; int bi = 0;
        for (int i = t; i < LL; i += 256) {
            float v = Ml[i];
            if (v > bv) { bv = v; bi = i; }
        }
        vals[t] = bv; vidx[t] = bi;
        __syncthreads();
        for (int s = 128; s > 0; s >>= 1) {
            if (t < s) {
                if (vals[t+s] > vals[t] ||
                    (vals[t+s] == vals[t] && vidx[t+s] < vidx[t])) {
                    vals[t] = vals[t+s]; vidx[t] = vidx[t+s];
                }
            }
            __syncthreads();
        }
        if (t == 0) {
            int w = vidx[0];
            idx[bh*UU + r] = w;
            Ml[w] = -1e30f;
            atomicOr(&map[(bh/HH)*LL + w], 1 << (bh % HH));
        }
        __syncthreads();
    }
}

// ---------------- K4: active-row attention (reg-dbuf QK^T, float4 PV) ------
__global__ __launch_bounds__(256) void active_attn(const float* __restrict__ Q,
                                                   const float* __restrict__ Kin,
                                                   const float* __restrict__ Vin,
                                                   const int* __restrict__ idx,
                                                   const float* __restrict__ vsum_part,
                                                   const float* __restrict__ w_out,
                                                   const float* __restrict__ b_out,
                                                   float* __restrict__ attn_o,
                                                   float* __restrict__ defo,
                                                   float* __restrict__ Wfull) {
    __shared__ float qs[64];
    __shared__ float w[LL];
    __shared__ float red[256];
    __shared__ float Kt[256][65];
    __shared__ float red4[16][16][4];
    int t = threadIdx.x;
    if (blockIdx.x >= BH*UU) {             // ---- default-output path ----
        int b = blockIdx.x - BH*UU;
        for (int i = t; i < DD; i += 256) {
            float s = 0.f;
            #pragma unroll
            for (int cc = 0; cc < 8; cc++)
                s += vsum_part[cc*2048 + (b*HH + (i >> 6))*64 + (i & 63)];
            w[i] = s * (1.0f/LL);
        }
        __syncthreads();
        for (int dp = t; dp < DD; dp += 256) {
            const float* wr = w_out + (size_t)dp*DD;
            float acc = b_out[dp];
            for (int d0 = 0; d0 < DD; d0 += 4) {
                float4 wv = *(const float4*)(wr + d0);
                acc += w[d0]*wv.x + w[d0+1]*wv.y + w[d0+2]*wv.z + w[d0+3]*wv.w;
            }
            defo[b*DD + dp] = acc;
        }
        return;
    }
    int e = blockIdx.x;
    int bh = e / UU;
    int b = bh / HH, h = bh % HH;
    int l = idx[e];
    if (t < 64) qs[t] = Q[(size_t)b*LL*DD + (size_t)l*DD + h*HD + t];
    const float* kb = Kin + (size_t)b*LL*DD + h*HD;
    int srow = t >> 4, scol = t & 15;      // stage layout: 16 rows x 16 float4
    float4 nx[16];
    #pragma unroll
    for (int i = 0; i < 16; i++)
        nx[i] = *(const float4*)(kb + (size_t)(srow + i*16)*DD + scol*4);
    #pragma unroll
    for (int i = 0; i < 16; i++)
        *(float4*)&Kt[srow + i*16][scol*4] = nx[i];
    __syncthreads();

    float s[8];
    float mx = -1e30f;
    #pragma unroll
    for (int p = 0; p < 8; p++) {
        if (p < 7) {                       // prefetch next round into regs
            #pragma unroll
            for (int i = 0; i < 16; i++)
                nx[i] = *(const float4*)(kb + (size_t)((p+1)*256 + srow + i*16)*DD + scol*4);
        }
        float acc = 0.f;
        for (int d0 = 0; d0 < 64; d0 += 4) {
            acc += qs[d0]*Kt[t][d0] + qs[d0+1]*Kt[t][d0+1]
                 + qs[d0+2]*Kt[t][d0+2] + qs[d0+3]*Kt[t][d0+3];
        }
        s[p] = acc * SCALE;
        mx = fmaxf(mx, s[p]);
        __syncthreads();                   // done reading Kt
        if (p < 7) {
            #pragma unroll
            for (int i = 0; i < 16; i++)
                *(float4*)&Kt[srow + i*16][scol*4] = nx[i];
        }
        __syncthreads();                   // Kt ready for next round
    }
    red[t] = mx; __syncthreads();
    for (int st = 128; st > 0; st >>= 1) { if (t < st) red[t] = fmaxf(red[t], red[t+st]); __syncthreads(); }
    mx = red[0]; __syncthreads();
    float lsum = 0.f;
    #pragma unroll
    for (int p = 0; p < 8; p++) { s[p] = __expf(s[p] - mx); lsum += s[p]; }
    red[t] = lsum; __syncthreads();
    for (int st = 128; st > 0; st >>= 1) { if (t < st) red[t] += red[t+st]; __syncthreads(); }
    float inv = 1.0f / red[0]; __syncthreads();
    float* wrow = Wfull + ((size_t)bh*LL + l) * LL;
    #pragma unroll
    for (int p = 0; p < 8; p++) {
        int m = (p << 8) + t;
        float wn = s[p] * inv;
        w[m] = wn;
        wrow[m] = wn;
    }
    __syncthreads();
    // ---- PV: float4 loads, 1KB/wave-instr ----
    const float4* vb4 = (const float4*)(Vin + (size_t)b*LL*DD + h*HD);
    int grp = t >> 4, d4 = t & 15;
    f32x4 acc = {0.f, 0.f, 0.f, 0.f};
    for (int it = 0; it < 128; it++) {
        int m = grp + it*16;
        float4 v4 = vb4[(size_t)m*128 + d4];
        float wm = w[m];
        acc[0] += wm * v4.x; acc[1] += wm * v4.y;
        acc[2] += wm * v4.z; acc[3] += wm * v4.w;
    }
    *(f32x4*)&red4[grp][d4][0] = acc;
    __syncthreads();
    if (t < 64) {
        int dq = t >> 2, comp = t & 3;
        float sum = 0.f;
        #pragma unroll
        for (int g = 0; g < 16; g++) sum += red4[g][dq][comp];
        attn_o[e*64 + t] = sum;
    }
}

// ---- K6: out = attn_output @ w_out^T + b_out, fused Wfull zero-fill -------
__global__ __launch_bounds__(256) void out_kernel(const float* __restrict__ defo,
                                                  const float* __restrict__ vsum_part,
                                                  const float* __restrict__ attn_o,
                                                  const int* __restrict__ idx,
                                                  const int* __restrict__ map,
                                                  const float* __restrict__ w_out,
                                                  const float* __restrict__ b_out,
                                                  float* __restrict__ out,
                                                  float* __restrict__ Wfull) {
    int l = blockIdx.x, b = blockIdx.y;
    int t = threadIdx.x;

    // ---- fill portion: 8 Wfull rows per block, skip active rows ----
    {
        int fid = b*LL + l;                        // 0..8191
        f32x4* Wz = (f32x4*)Wfull;
        const f32x4 z = {0.f, 0.f, 0.f, 0.f};
        #pragma unroll
        for (int rr = 0; rr < 8; rr++) {
            int R = fid*8 + rr;                    // global Wfull row, 0..65535
            int bh2 = R >> 11, l2 = R & 2047;
            int b2 = bh2 >> 3, h2 = bh2 & 7;
            if (!((map[b2*LL + l2] >> h2) & 1)) {
                f32x4* rowp = Wz + (size_t)R*512;  // 2048 f32 = 512 f32x4
                rowp[t] = z;
                rowp[t + 256] = z;
            }
        }
    }

    // ---- output-row portion ----
    float* orow = out + ((size_t)b*LL + l) * DD;
    int mp = map[b*LL + l];
    if (mp == 0) {
        const float* dr = defo + b*DD;
        orow[t] = dr[t]; orow[t + 256] = dr[t + 256];
        return;
    }
    __shared__ float x[DD];
    for (int i = t; i < DD; i += 256) {
        float s = 0.f;
        #pragma unroll
        for (int cc = 0; cc < 8; cc++)
            s += vsum_part[cc*2048 + (b*HH + (i >> 6))*64 + (i & 63)];
        x[i] = s * (1.0f/LL);
    }
    __syncthreads();
    if (t < 64) {
        for (int h = 0; h < HH; h++) if (mp & (1 << h)) {
            int bh = b*HH + h;
            int e = bh*UU;
            for (int j = 0; j < UU; j++) if (idx[bh*UU + j] == l) { e = bh*UU + j; break; }
            x[h*64 + t] = attn_o[e*64 + t];
        }
    }
    __syncthreads();
    for (int dp = t; dp < DD; dp += 256) {
        const float* wr = w_out + (size_t)dp*DD;
        float acc = b_out[dp];
        for (int d0 = 0; d0 < DD; d0 += 4) {
            float4 wv = *(const float4*)(wr + d0);
            acc += x[d0]*wv.x + x[d0+1]*wv.y + x[d0+2]*wv.z + x[d0+3]*wv.w;
        }
        orow[dp] = acc;
    }
}

extern "C" void kernel_launch(void* const* d_in, const int* in_sizes, int n_in,
                              void* d_out, int out_size, void* d_ws, size_t ws_size,
                              hipStream_t stream) {
    const float* Q     = (const float*)d_in[0];
    const float* Kin   = (const float*)d_in[1];
    const float* Vin   = (const float*)d_in[2];
    const float* w_out = (const float*)d_in[3];
    const float* b_out = (const float*)d_in[4];

    float* out   = (float*)d_out;
    float* Wfull = out + (size_t)BB*LL*DD;

    char* ws = (char*)d_ws;
    float*   vsum_part = (float*)(ws);                     // [8][32][64] 64KB
    float*   ksum_part = (float*)(ws + 65536);             // [8][32][64] 64KB
    float*   M         = (float*)(ws + 131072);            // [32][2048] 256KB
    int*     idx       = (int*)  (ws + 393216);            // [32][8]
    float*   attn_o    = (float*)(ws + 394240);            // [256][64] 64KB
    int*     map       = (int*)  (ws + 459776);            // [4][2048] 32KB
    float*   defo      = (float*)(ws + 493568);            // [4][512]  8KB
    ushortT* KhiG      = (ushortT*)(ws + (1u<<20));        // 8 MB tile images

    prep<<<1280, 256, 0, stream>>>(Kin, Vin, vsum_part, ksum_part, KhiG, map);
    m_mfma<<<dim3(16, BH), 256, 0, stream>>>(Q, KhiG, ksum_part, M);
    top8<<<BH, 256, 0, stream>>>(M, idx, map);
    active_attn<<<BH*UU + BB, 256, 0, stream>>>(Q, Kin, Vin, idx, vsum_part, w_out, b_out,
                                                attn_o, defo, Wfull);
    out_kernel<<<dim3(LL, BB), 256, 0, stream>>>(defo, vsum_part, attn_o, idx, map,
                                                 w_out, b_out, out, Wfull);
}

// Round 17
// 347.417 us; speedup vs baseline: 1.4117x; 1.0655x over previous
//
#include <hip/hip_runtime.h>
#include <hip/hip_bf16.h>

#define BB 4
#define LL 2048
#define DD 512
#define HH 8
#define HD 64
#define UU 8
#define BH (BB*HH)
#define SCALE 0.125f
#define ASCALE 0.18033688011112042f   // 0.125 * log2(e)

typedef __attribute__((ext_vector_type(8))) short short8;
typedef __attribute__((ext_vector_type(4))) float f32x4;
typedef unsigned short ushortT;

#define GLDS(gp, lp) __builtin_amdgcn_global_load_lds( \
    (const __attribute__((address_space(1))) void*)(gp), \
    (__attribute__((address_space(3))) void*)(lp), 16, 0, 0)

__device__ __forceinline__ unsigned short bf16_rne(float x) {
    unsigned int u = __float_as_uint(x);
    unsigned int r = u + 0x7FFFu + ((u >> 16) & 1u);
    return (unsigned short)(r >> 16);
}

// ---- K0: fused {kv partial sums (+map zero)} + {K hi-bf16 images} ---------
__global__ __launch_bounds__(256) void prep(const float* __restrict__ Kin,
                                            const float* __restrict__ Vin,
                                            float* __restrict__ vsum_part,
                                            float* __restrict__ ksum_part,
                                            ushortT* __restrict__ KhiG,
                                            int* __restrict__ map) {
    int t = threadIdx.x;
    if (blockIdx.x < 256) {                    // ---- kv partial-sum path ----
        int blk = blockIdx.x;
        if (blk < 32) map[blk*256 + t] = 0;    // zero head map (8192 ints)
        int bh = blk & 31, chunk = blk >> 5;
        int b = bh / HH, h = bh % HH;
        int d = t & 63; int g = t >> 6;
        const float* kb = Kin + (size_t)b*LL*DD + h*HD + d;
        const float* vb = Vin + (size_t)b*LL*DD + h*HD + d;
        float ak = 0.f, av = 0.f;
        for (int l = chunk*256 + g; l < chunk*256 + 256; l += 4) {
            ak += kb[(size_t)l*DD]; av += vb[(size_t)l*DD];
        }
        __shared__ float sk[4][64], sv[4][64];
        sk[g][d] = ak; sv[g][d] = av;
        __syncthreads();
        if (g == 0) {
            ksum_part[chunk*2048 + bh*64 + d] = sk[0][d]+sk[1][d]+sk[2][d]+sk[3][d];
            vsum_part[chunk*2048 + bh*64 + d] = sv[0][d]+sv[1][d]+sv[2][d]+sv[3][d];
        }
        return;
    }
    int blk = blockIdx.x - 256;                // ---- K hi-image path ----
    int bh = blk >> 5, tile = blk & 31;
    int b = bh / HH, h = bh % HH;
    const float* kb = Kin + (size_t)b*LL*DD + h*HD;
    #pragma unroll
    for (int i = 0; i < 4; i++) {
        int f = t + i*256;
        int row = f >> 4, col4 = f & 15;
        float4 kv = *(const float4*)(kb + (size_t)(tile*64 + row)*DD + col4*4);
        float xs[4] = {kv.x, kv.y, kv.z, kv.w};
        unsigned short hb[4];
        #pragma unroll
        for (int j = 0; j < 4; j++) hb[j] = bf16_rne(xs[j]);
        int off = row*64 + (((col4>>1) ^ (row&7))<<3) + (col4&1)*4;
        uint2 uh; uh.x = hb[0] | ((unsigned)hb[1]<<16); uh.y = hb[2] | ((unsigned)hb[3]<<16);
        *(uint2*)&KhiG[(size_t)blk*4096 + off] = uh;
    }
}

// ---- K2: M_measure via 2-term split-bf16 MFMA (k_hi only in LDS) ----------
__global__ __launch_bounds__(256) void m_mfma(const float* __restrict__ Q,
                                              const ushortT* __restrict__ KhiG,
                                              const float* __restrict__ ksum_part,
                                              float* __restrict__ M) {
    int qt = blockIdx.x;
    int bh = blockIdx.y; int b = bh / HH, h = bh % HH;
    const int t = threadIdx.x;
    const int lane = t & 63, w = t >> 6;
    const int c = lane & 15, G = lane >> 4;

    __shared__ unsigned short kHi[2][4096];
    __shared__ float ksLds[64];
    __shared__ float sm[128];

    const float* qb = Q + (size_t)b*LL*DD + h*HD;
    const char* khg = (const char*)(KhiG + (size_t)bh*32*4096);

    short8 a_hi[2][2], a_lo[2][2];
    #pragma unroll
    for (int g = 0; g < 2; g++) {
        int qrow = qt*128 + w*32 + g*16 + c;
        const float* qr = qb + (size_t)qrow*DD + G*8;
        #pragma unroll
        for (int dh = 0; dh < 2; dh++) {
            float4 x0 = *(const float4*)(qr + dh*32);
            float4 x1 = *(const float4*)(qr + dh*32 + 4);
            float x[8] = {x0.x,x0.y,x0.z,x0.w, x1.x,x1.y,x1.z,x1.w};
            short8 hi, lo;
            #pragma unroll
            for (int j = 0; j < 8; j++) {
                float xs = x[j] * ASCALE;
                unsigned short hb = bf16_rne(xs);
                float hf = __uint_as_float((unsigned int)hb << 16);
                hi[j] = (short)hb;
                lo[j] = (short)bf16_rne(xs - hf);
            }
            a_hi[g][dh] = hi; a_lo[g][dh] = lo;
        }
    }
    if (t < 64) {
        float s = 0.f;
        #pragma unroll
        for (int cc = 0; cc < 8; cc++) s += ksum_part[cc*2048 + bh*64 + t];
        ksLds[t] = s;
    }

    {
        char* dH = (char*)&kHi[0][0];
        unsigned o0 = w*1024, o1 = w*1024 + 4096;
        GLDS(khg + o0 + lane*16, dH + o0);
        GLDS(khg + o1 + lane*16, dH + o1);
    }
    float se[2][4] = {};
    __syncthreads();

    for (int r = 0; r < 32; r++) {
        int p = r & 1;
        if (r < 31) {
            const char* sH = khg + (size_t)(r+1)*8192;
            char* dH = (char*)&kHi[p^1][0];
            unsigned o0 = w*1024, o1 = w*1024 + 4096;
            GLDS(sH + o0 + lane*16, dH + o0);
            GLDS(sH + o1 + lane*16, dH + o1);
        }
        #pragma unroll
        for (int kt = 0; kt < 4; kt++) {
            int rowIn = kt*16 + c;
            int sw = rowIn & 7;
            int base = rowIn*64;
            short8 bh0 = *(const short8*)&kHi[p][base + ((G       ^ sw)<<3)];
            short8 bh1 = *(const short8*)&kHi[p][base + (((G + 4) ^ sw)<<3)];
            #pragma unroll
            for (int g = 0; g < 2; g++) {
                f32x4 acc = {0.f, 0.f, 0.f, 0.f};
                acc = __builtin_amdgcn_mfma_f32_16x16x32_bf16(a_hi[g][0], bh0, acc, 0, 0, 0);
                acc = __builtin_amdgcn_mfma_f32_16x16x32_bf16(a_hi[g][1], bh1, acc, 0, 0, 0);
                acc = __builtin_amdgcn_mfma_f32_16x16x32_bf16(a_lo[g][0], bh0, acc, 0, 0, 0);
                acc = __builtin_amdgcn_mfma_f32_16x16x32_bf16(a_lo[g][1], bh1, acc, 0, 0, 0);
                #pragma unroll
                for (int q4 = 0; q4 < 4; q4++) se[g][q4] += exp2f(acc[q4]);
            }
        }
        __syncthreads();
    }

    #pragma unroll
    for (int g = 0; g < 2; g++)
        #pragma unroll
        for (int q4 = 0; q4 < 4; q4++) {
            float v = se[g][q4];
            v += __shfl_xor(v, 1);
            v += __shfl_xor(v, 2);
            v += __shfl_xor(v, 4);
            v += __shfl_xor(v, 8);
            se[g][q4] = v;
        }
    if (c == 0) {
        #pragma unroll
        for (int g = 0; g < 2; g++)
            #pragma unroll
            for (int q4 = 0; q4 < 4; q4++)
                sm[w*32 + g*16 + G*4 + q4] = se[g][q4];
    }
    __syncthreads();
    if (t < 128) {
        int qrow = qt*128 + t;
        const float* qr = qb + (size_t)qrow*DD;
        float dot = 0.f;
        for (int d0 = 0; d0 < 64; d0 += 4) {
            float4 qv = *(const float4*)(qr + d0);
            dot += qv.x*ksLds[d0] + qv.y*ksLds[d0+1] + qv.z*ksLds[d0+2] + qv.w*ksLds[d0+3];
        }
        M[bh*LL + qrow] = __logf(sm[t]) - __logf((float)LL) - dot * (SCALE/(float)LL);
    }
}

// ---- K3: top-8 per (b,h) -> map bits; blocks 32..35 compute defo ----------
__global__ __launch_bounds__(256) void top8_defo(const float* __restrict__ M,
                                                 const float* __restrict__ vsum_part,
                                                 const float* __restrict__ w_out,
                                                 const float* __restrict__ b_out,
                                                 int* __restrict__ map,
                                                 float* __restrict__ defo) {
    int t = threadIdx.x;
    __shared__ float Ml[LL];
    __shared__ float vals[256];
    __shared__ int   vidx[256];
    if (blockIdx.x >= BH) {                    // ---- defo path ----
        int b = blockIdx.x - BH;
        for (int i = t; i < DD; i += 256) {
            float s = 0.f;
            #pragma unroll
            for (int cc = 0; cc < 8; cc++)
                s += vsum_part[cc*2048 + (b*HH + (i >> 6))*64 + (i & 63)];
            Ml[i] = s * (1.0f/LL);
        }
        __syncthreads();
        for (int dp = t; dp < DD; dp += 256) {
            const float* wr = w_out + (size_t)dp*DD;
            float acc = b_out[dp];
            for (int d0 = 0; d0 < DD; d0 += 4) {
                float4 wv = *(const float4*)(wr + d0);
                acc += Ml[d0]*wv.x + Ml[d0+1]*wv.y + Ml[d0+2]*wv.z + Ml[d0+3]*wv.w;
            }
            defo[b*DD + dp] = acc;
        }
        return;
    }
    int bh = blockIdx.x;
    for (int i = t; i < LL; i += 256) Ml[i] = M[bh*LL + i];
    __syncthreads();
    for (int r = 0; r < UU; r++) {
        float bv = -1e30f; int bi = 0;
        for (int i = t; i < LL; i += 256) {
            float v = Ml[i];
            if (v > bv) { bv = v; bi = i; }
        }
        vals[t] = bv; vidx[t] = bi;
        __syncthreads();
        for (int s = 128; s > 0; s >>= 1) {
            if (t < s) {
                if (vals[t+s] > vals[t] ||
                    (vals[t+s] == vals[t] && vidx[t+s] < vidx[t])) {
                    vals[t] = vals[t+s]; vidx[t] = vidx[t+s];
                }
            }
            __syncthreads();
        }
        if (t == 0) {
            int w = vidx[0];
            Ml[w] = -1e30f;
            atomicOr(&map[(bh/HH)*LL + w], 1 << (bh % HH));
        }
        __syncthreads();
    }
}

// ---- K6: mega out = fill Wfull + inline active attention + output GEMM ----
__global__ __launch_bounds__(256) void out_mega(const float* __restrict__ Q,
                                                const float* __restrict__ Kin,
                                                const float* __restrict__ Vin,
                                                const float* __restrict__ defo,
                                                const float* __restrict__ vsum_part,
                                                const int* __restrict__ map,
                                                const float* __restrict__ w_out,
                                                const float* __restrict__ b_out,
                                                float* __restrict__ out,
                                                float* __restrict__ Wfull) {
    int l = blockIdx.x, b = blockIdx.y;
    int t = threadIdx.x;

    // ---- fill portion: 8 Wfull rows per block, skip active rows ----
    {
        int fid = b*LL + l;                        // 0..8191
        f32x4* Wz = (f32x4*)Wfull;
        const f32x4 z = {0.f, 0.f, 0.f, 0.f};
        #pragma unroll
        for (int rr = 0; rr < 8; rr++) {
            int R = fid*8 + rr;                    // global Wfull row, 0..65535
            int bh2 = R >> 11, l2 = R & 2047;
            int b2 = bh2 >> 3, h2 = bh2 & 7;
            if (!((map[b2*LL + l2] >> h2) & 1)) {
                f32x4* rowp = Wz + (size_t)R*512;
                rowp[t] = z;
                rowp[t + 256] = z;
            }
        }
    }

    float* orow = out + ((size_t)b*LL + l) * DD;
    int mp = map[b*LL + l];
    if (mp == 0) {
        const float* dr = defo + b*DD;
        orow[t] = dr[t]; orow[t + 256] = dr[t + 256];
        return;
    }

    // ---- active row: x = defaults, then overwrite active heads ----
    __shared__ float x[DD];
    __shared__ float qs[64];
    __shared__ float w[LL];
    __shared__ float red[256];
    __shared__ float red4[16][16][4];
    for (int i = t; i < DD; i += 256) {
        float s = 0.f;
        #pragma unroll
        for (int cc = 0; cc < 8; cc++)
            s += vsum_part[cc*2048 + (b*HH + (i >> 6))*64 + (i & 63)];
        x[i] = s * (1.0f/LL);
    }
    __syncthreads();

    for (int h = 0; h < HH; h++) if (mp & (1 << h)) {
        int bh = b*HH + h;
        if (t < 64) qs[t] = Q[(size_t)b*LL*DD + (size_t)l*DD + h*HD + t];
        __syncthreads();
        const float* kb = Kin + (size_t)b*LL*DD + h*HD;
        float s[8];
        float mx = -1e30f;
        #pragma unroll
        for (int p = 0; p < 8; p++) {
            int m = t + p*256;
            const float* kr = kb + (size_t)m*DD;
            float acc = 0.f;
            for (int d0 = 0; d0 < 64; d0 += 4) {
                float4 kv = *(const float4*)(kr + d0);
                acc += qs[d0]*kv.x + qs[d0+1]*kv.y + qs[d0+2]*kv.z + qs[d0+3]*kv.w;
            }
            s[p] = acc * SCALE;
            mx = fmaxf(mx, s[p]);
        }
        red[t] = mx; __syncthreads();
        for (int st = 128; st > 0; st >>= 1) { if (t < st) red[t] = fmaxf(red[t], red[t+st]); __syncthreads(); }
        mx = red[0]; __syncthreads();
        float lsum = 0.f;
        #pragma unroll
        for (int p = 0; p < 8; p++) { s[p] = __expf(s[p] - mx); lsum += s[p]; }
        red[t] = lsum; __syncthreads();
        for (int st = 128; st > 0; st >>= 1) { if (t < st) red[t] += red[t+st]; __syncthreads(); }
        float inv = 1.0f / red[0]; __syncthreads();
        float* wrow = Wfull + ((size_t)bh*LL + l) * LL;
        #pragma unroll
        for (int p = 0; p < 8; p++) {
            int m = (p << 8) + t;
            float wn = s[p] * inv;
            w[m] = wn;
            wrow[m] = wn;
        }
        __syncthreads();
        const float4* vb4 = (const float4*)(Vin + (size_t)b*LL*DD + h*HD);
        int grp = t >> 4, d4 = t & 15;
        f32x4 acc4 = {0.f, 0.f, 0.f, 0.f};
        for (int it = 0; it < 128; it++) {
            int m = grp + it*16;
            float4 v4 = vb4[(size_t)m*128 + d4];
            float wm = w[m];
            acc4[0] += wm * v4.x; acc4[1] += wm * v4.y;
            acc4[2] += wm * v4.z; acc4[3] += wm * v4.w;
        }
        *(f32x4*)&red4[grp][d4][0] = acc4;
        __syncthreads();
        if (t < 64) {
            int dq = t >> 2, comp = t & 3;
            float sum = 0.f;
            #pragma unroll
            for (int g = 0; g < 16; g++) sum += red4[g][dq][comp];
            x[h*64 + t] = sum;
        }
        __syncthreads();
    }

    for (int dp = t; dp < DD; dp += 256) {
        const float* wr = w_out + (size_t)dp*DD;
        float acc = b_out[dp];
        for (int d0 = 0; d0 < DD; d0 += 4) {
            float4 wv = *(const float4*)(wr + d0);
            acc += x[d0]*wv.x + x[d0+1]*wv.y + x[d0+2]*wv.z + x[d0+3]*wv.w;
        }
        orow[dp] = acc;
    }
}

extern "C" void kernel_launch(void* const* d_in, const int* in_sizes, int n_in,
                              void* d_out, int out_size, void* d_ws, size_t ws_size,
                              hipStream_t stream) {
    const float* Q     = (const float*)d_in[0];
    const float* Kin   = (const float*)d_in[1];
    const float* Vin   = (const float*)d_in[2];
    const float* w_out = (const float*)d_in[3];
    const float* b_out = (const float*)d_in[4];

    float* out   = (float*)d_out;
    float* Wfull = out + (size_t)BB*LL*DD;

    char* ws = (char*)d_ws;
    float*   vsum_part = (float*)(ws);                     // [8][32][64] 64KB
    float*   ksum_part = (float*)(ws + 65536);             // [8][32][64] 64KB
    float*   M         = (float*)(ws + 131072);            // [32][2048] 256KB
    int*     map       = (int*)  (ws + 393216);            // [4][2048] 32KB
    float*   defo      = (float*)(ws + 425984);            // [4][512]  8KB
    ushortT* KhiG      = (ushortT*)(ws + (1u<<20));        // 8 MB tile images

    prep<<<1280, 256, 0, stream>>>(Kin, Vin, vsum_part, ksum_part, KhiG, map);
    m_mfma<<<dim3(16, BH), 256, 0, stream>>>(Q, KhiG, ksum_part, M);
    top8_defo<<<BH + BB, 256, 0, stream>>>(M, vsum_part, w_out, b_out, map, defo);
    out_mega<<<dim3(LL, BB), 256, 0, stream>>>(Q, Kin, Vin, defo, vsum_part, map,
                                               w_out, b_out, out, Wfull);
}